// Round 3
// baseline (124.090 us; speedup 1.0000x reference)
//
#include <hip/hip_runtime.h>
#include <hip/hip_bf16.h>
#include <stdint.h>

// Problem constants
#define KD 2304    // K = C*3*3 = 256*9
#define LD 3136    // L = 56*56
#define ND 256     // output channels
#define MD 25088   // B*L = 8*3136
#define CD 256     // input channels
#define PW 58      // padded width
#define PP 3364    // padded plane = 58*58

typedef __bf16 bf16x8 __attribute__((ext_vector_type(8)));
typedef float f32x4 __attribute__((ext_vector_type(4)));
typedef unsigned short u16x8 __attribute__((ext_vector_type(8)));

__device__ __forceinline__ void gload_lds16(const void* g, void* l) {
  __builtin_amdgcn_global_load_lds(
      (const __attribute__((address_space(1))) unsigned int*)g,
      (__attribute__((address_space(3))) unsigned int*)l, 16, 0, 0);
}

// ---------------- Phase -1: zero-pad x into [B][C][58][58] ----------------
__global__ __launch_bounds__(256) void pad_kernel(
    const float* __restrict__ x, float* __restrict__ xpad) {
  const int plane = blockIdx.x;                  // b*C + c
  const float* src = x + (size_t)plane * LD;
  float* dst = xpad + (size_t)plane * PP;
  for (int idx = threadIdx.x; idx < PP; idx += 256) {
    const int ip = idx / PW;
    const int jp = idx - ip * PW;
    float v = 0.f;
    if (ip >= 1 && ip <= 56 && jp >= 1 && jp <= 56)
      v = src[(ip - 1) * 56 + (jp - 1)];
    dst[idx] = v;
  }
}

// ---------------- Phase 0: weight fake-quant -> wqT [N][K] bf16 ----------------
__global__ __launch_bounds__(256) void quant_w_kernel(
    const float* __restrict__ w, __hip_bfloat16* __restrict__ wqT) {
  const int gk = blockIdx.x % 72;
  const int gn = blockIdx.x / 72;
  const int n = gn * 32 + (threadIdx.x >> 3);
  const int k = gk * 32 + (threadIdx.x & 7) * 4;
  const float4 v = *(const float4*)(w + (size_t)n * KD + k);
  float a = fmaxf(fmaxf(fabsf(v.x), fabsf(v.y)), fmaxf(fabsf(v.z), fabsf(v.w)));
#pragma unroll
  for (int m = 1; m <= 32; m <<= 1) a = fmaxf(a, __shfl_xor(a, m, 64));
  __shared__ float red[4];
  if ((threadIdx.x & 63) == 0) red[threadIdx.x >> 6] = a;
  __syncthreads();
  const float mx = fmaxf(fmaxf(red[0], red[1]), fmaxf(red[2], red[3]));
  const float r63 = (mx == 0.f) ? 0.f : 63.f / mx;
  const float scale = mx * (1.f / 63.f);
  float q0 = fminf(fmaxf(rintf(v.x * r63), -63.f), 63.f);
  float q1 = fminf(fmaxf(rintf(v.y * r63), -63.f), 63.f);
  float q2 = fminf(fmaxf(rintf(v.z * r63), -63.f), 63.f);
  float q3 = fminf(fmaxf(rintf(v.w * r63), -63.f), 63.f);
  ushort4 o;
  o.x = __builtin_bit_cast(unsigned short, __float2bfloat16(q0 * scale));
  o.y = __builtin_bit_cast(unsigned short, __float2bfloat16(q1 * scale));
  o.z = __builtin_bit_cast(unsigned short, __float2bfloat16(q2 * scale));
  o.w = __builtin_bit_cast(unsigned short, __float2bfloat16(q3 * scale));
  *(ushort4*)((unsigned short*)wqT + (size_t)n * KD + k) = o;
}

// ---------------- Fused: unfold+quant-A (LDS) + GEMM + bias ----------------
// BM=64 (rows m), BN=256 (= all N), BK=64, 4 waves.
// Waves 0-1: quantize A granules (row=lane, 32-k half=waveid) -> swizzled As.
// Waves 2-3: stage wqT tile via global_load_lds with pre-swizzled source.
// Swizzle (both sides): byte ^= ((row&7)<<4) within each 128B row.
__global__ __launch_bounds__(256) void fused_gemm_kernel(
    const float* __restrict__ xpad, const __hip_bfloat16* __restrict__ wqT,
    const float* __restrict__ bias, float* __restrict__ out) {
  __shared__ __hip_bfloat16 As[64 * 64];    // 8KB  [m row][k], swizzled
  __shared__ __hip_bfloat16 Ns[256 * 64];   // 32KB [n row][k], swizzled
  const int tid = threadIdx.x;
  const int lane = tid & 63;
  const int w = tid >> 6;         // 0..3
  const int m0 = blockIdx.x * 64;

  // quant-A geometry (waves 0-1): row = lane (64 rows never straddle b: 3136%64==0)
  const int gm = m0 + lane;
  const int b = gm / LD;
  const int l = gm - b * LD;
  const int i = l / 56;
  const int j = l - i * 56;
  const float* pb = xpad + (size_t)b * CD * PP;
  const int p0 = i * PW + j;      // top-left of 3x3 window in padded plane

  // B staging source column pre-swizzle (waves 2-3)
  const int colsw = ((lane & 7) ^ (lane >> 3)) * 8;   // element offset
  const int lq = lane & 15;
  const int hv = lane >> 4;

  f32x4 acc[4][4] = {};

  for (int kt = 0; kt < 36; ++kt) {
    const int k0 = kt * 64;
    if (w < 2) {
      // ---- quantize granule [k0 + w*32, +32) of row `lane` ----
      const int kbase = __builtin_amdgcn_readfirstlane(k0 + w * 32);
      int c = kbase / 9;
      int kp = kbase - 9 * c;
      float v[32];
      float mx = 0.f;
#pragma unroll
      for (int t = 0; t < 32; ++t) {
        const int di = (kp >= 6) ? 2 : ((kp >= 3) ? 1 : 0);
        const int dj = kp - 3 * di;
        const int off = c * PP + di * PW + dj;        // wave-uniform scalar
        const float val = pb[p0 + off];
        v[t] = val;
        mx = fmaxf(mx, __builtin_fabsf(val));
        if (++kp == 9) { kp = 0; ++c; }
      }
      const float r63 = (mx == 0.f) ? 0.f : 63.f / mx;
      const float scale = mx * (1.f / 63.f);
      const unsigned sw = (unsigned)((lane & 7) << 4);
      const unsigned rbase = (unsigned)lane * 128 + (unsigned)(w * 64);  // w*32 elems = w*64 bytes
#pragma unroll
      for (int s = 0; s < 4; ++s) {
        u16x8 o;
#pragma unroll
        for (int e = 0; e < 8; ++e) {
          float q = rintf(v[s * 8 + e] * r63);
          q = fminf(fmaxf(q, -63.f), 63.f);
          o[e] = __builtin_bit_cast(unsigned short, __float2bfloat16(q * scale));
        }
        const unsigned byte = (rbase + (unsigned)(s * 16)) ^ sw;
        *(u16x8*)((char*)As + byte) = o;
      }
    } else {
      // ---- stage B tile: 256 rows x 64 k = 32KB, 16 calls/wave ----
      const int wv = w - 2;
#pragma unroll
      for (int s = 0; s < 16; ++s) {
        const int seg = s * 2 + wv;                   // 0..31 (1KB = 8 rows each)
        const int row = seg * 8 + (lane >> 3);
        gload_lds16(wqT + (size_t)row * KD + k0 + colsw,
                    (char*)Ns + seg * 1024 + (lane & 7) * 16 + (lane >> 3) * 128);
      }
    }
    __syncthreads();   // staging visible (compiler drains vmcnt/lgkmcnt)

    // ---- MFMA: wave w owns n-slice [w*64, w*64+64) ----
#pragma unroll
    for (int kk = 0; kk < 2; ++kk) {
      const int ko = kk * 32 + hv * 8;                // element offset in k
      const unsigned kobyte = (unsigned)(ko * 2);
      const unsigned swq = (unsigned)((lq & 7) << 4);
      bf16x8 af[4], bfr[4];
#pragma unroll
      for (int ifr = 0; ifr < 4; ++ifr) {
        const unsigned r = (unsigned)(w * 64 + ifr * 16 + lq);
        af[ifr] = *(const bf16x8*)((const char*)Ns + ((r * 128 + kobyte) ^ swq));
      }
#pragma unroll
      for (int jfr = 0; jfr < 4; ++jfr) {
        const unsigned r = (unsigned)(jfr * 16 + lq);
        bfr[jfr] = *(const bf16x8*)((const char*)As + ((r * 128 + kobyte) ^ swq));
      }
#pragma unroll
      for (int ifr = 0; ifr < 4; ++ifr)
#pragma unroll
        for (int jfr = 0; jfr < 4; ++jfr)
          acc[ifr][jfr] = __builtin_amdgcn_mfma_f32_16x16x32_bf16(
              af[ifr], bfr[jfr], acc[ifr][jfr], 0, 0, 0);
    }
    __syncthreads();   // MFMA reads done before next-tile overwrite
  }

  // ---- Epilogue: D row = n = w*64 + ifr*16 + hv*4 + r, col = m ----
#pragma unroll
  for (int ifr = 0; ifr < 4; ++ifr) {
    const int nb = w * 64 + ifr * 16 + hv * 4;
    const float4 b4 = *(const float4*)&bias[nb];
#pragma unroll
    for (int jfr = 0; jfr < 4; ++jfr) {
      const int m = m0 + jfr * 16 + lq;
      const int bb = m / LD;
      const int ll = m - bb * LD;
      float* op = out + ((size_t)bb * ND + nb) * LD + ll;
      op[0]      = acc[ifr][jfr].x + b4.x;
      op[LD]     = acc[ifr][jfr].y + b4.y;
      op[2 * LD] = acc[ifr][jfr].z + b4.z;
      op[3 * LD] = acc[ifr][jfr].w + b4.w;
    }
  }
}

extern "C" void kernel_launch(void* const* d_in, const int* in_sizes, int n_in,
                              void* d_out, int out_size, void* d_ws, size_t ws_size,
                              hipStream_t stream) {
  const float* x = (const float*)d_in[0];
  const float* wgt = (const float*)d_in[1];
  const float* bias = (const float*)d_in[2];
  float* out = (float*)d_out;

  float* xpad = (float*)d_ws;                                   // 8*256*3364*4 = 27,557,888 B
  __hip_bfloat16* wqT = (__hip_bfloat16*)((char*)d_ws + 27557888);  // 256*2304*2 = 1,179,648 B

  pad_kernel<<<8 * CD, 256, 0, stream>>>(x, xpad);
  quant_w_kernel<<<576, 256, 0, stream>>>(wgt, wqT);
  fused_gemm_kernel<<<MD / 64, 256, 0, stream>>>(xpad, wqT, bias, out);
}

// Round 4
// 106.078 us; speedup vs baseline: 1.1698x; 1.1698x over previous
//
#include <hip/hip_runtime.h>
#include <hip/hip_bf16.h>
#include <stdint.h>

// Problem constants
#define KD 2304    // K = C*3*3
#define LD 3136    // L = 56*56
#define ND 256     // output channels
#define MD 25088   // B*L
#define CD 256     // input channels
#define PITCH 64   // padded row pitch (floats), 16B-aligned rows
#define PROWS 58
#define PLANE (PROWS * PITCH)   // 3712 floats per padded channel plane

typedef __bf16 bf16x8 __attribute__((ext_vector_type(8)));
typedef float f32x4 __attribute__((ext_vector_type(4)));
typedef float f32x4u __attribute__((ext_vector_type(4), aligned(4)));
typedef unsigned short u16x8 __attribute__((ext_vector_type(8)));

__device__ __forceinline__ void gload_lds16(const void* g, void* l) {
  __builtin_amdgcn_global_load_lds(
      (const __attribute__((address_space(1))) unsigned int*)g,
      (__attribute__((address_space(3))) unsigned int*)l, 16, 0, 0);
}

// ---------------- Phase -1: zero-pad x into [B*C][58][PITCH=64] ----------------
__global__ __launch_bounds__(256) void pad_kernel(
    const float* __restrict__ x, float* __restrict__ xpad) {
  const int plane = blockIdx.x;                 // b*C + c
  const float* src = x + (size_t)plane * LD;
  float* dst = xpad + (size_t)plane * PLANE;
  const int cc4 = (threadIdx.x & 15) * 4;       // 0..60 step 4
  const int r0 = threadIdx.x >> 4;              // 0..15
#pragma unroll
  for (int p = 0; p < 4; ++p) {
    const int r = r0 + p * 16;
    if (r >= PROWS) continue;
    f32x4 o = {0.f, 0.f, 0.f, 0.f};
    if (r >= 1 && r <= 56) {
      const float* srow = src + (r - 1) * 56;
      if (cc4 == 0) {                       // cols 0..3 <- [0, s0, s1, s2]
        f32x4u v = *(const f32x4u*)(srow);
        o[1] = v[0]; o[2] = v[1]; o[3] = v[2];
      } else if (cc4 <= 52) {               // cols cc4..cc4+3 <- s[cc4-1..cc4+2]
        o = *(const f32x4u*)(srow + cc4 - 1);
      } else if (cc4 == 56) {               // col 56 <- s55, cols 57.. = 0
        f32x4u v = *(const f32x4u*)(srow + 52);
        o[0] = v[3];
      }                                     // cc4 == 60 -> zeros
    }
    *(f32x4*)(dst + r * PITCH + cc4) = o;
  }
}

// ---------------- Phase 0: weight fake-quant -> wqT [N][K] bf16 ----------------
__global__ __launch_bounds__(256) void quant_w_kernel(
    const float* __restrict__ w, __hip_bfloat16* __restrict__ wqT) {
  const int gk = blockIdx.x % 72;
  const int gn = blockIdx.x / 72;
  const int n = gn * 32 + (threadIdx.x >> 3);
  const int k = gk * 32 + (threadIdx.x & 7) * 4;
  const float4 v = *(const float4*)(w + (size_t)n * KD + k);
  float a = fmaxf(fmaxf(fabsf(v.x), fabsf(v.y)), fmaxf(fabsf(v.z), fabsf(v.w)));
#pragma unroll
  for (int m = 1; m <= 32; m <<= 1) a = fmaxf(a, __shfl_xor(a, m, 64));
  __shared__ float red[4];
  if ((threadIdx.x & 63) == 0) red[threadIdx.x >> 6] = a;
  __syncthreads();
  const float mx = fmaxf(fmaxf(red[0], red[1]), fmaxf(red[2], red[3]));
  const float r63 = (mx == 0.f) ? 0.f : 63.f / mx;
  const float scale = mx * (1.f / 63.f);
  ushort4 o;
  o.x = __builtin_bit_cast(unsigned short, __float2bfloat16(rintf(v.x * r63) * scale));
  o.y = __builtin_bit_cast(unsigned short, __float2bfloat16(rintf(v.y * r63) * scale));
  o.z = __builtin_bit_cast(unsigned short, __float2bfloat16(rintf(v.z * r63) * scale));
  o.w = __builtin_bit_cast(unsigned short, __float2bfloat16(rintf(v.w * r63) * scale));
  *(ushort4*)((unsigned short*)wqT + (size_t)n * KD + k) = o;
}

// ---- quantize one 32-k granule of one unfolded row, static channel/tap phase ----
// KP0 = kbase % 9 (compile-time). Loads f32x4 windows from padded planes,
// writes 4x16B swizzled chunks into As row.
template <int KP0>
__device__ __forceinline__ void quant_granule(
    const float* __restrict__ pb, int p0, int c0,
    char* as_row, unsigned cbase, unsigned swz) {
  constexpr int NCH = (KP0 + 31) / 9 + 1;   // 4 or 5 channels touched
  f32x4u win[5][3];
#pragma unroll
  for (int dc = 0; dc < NCH; ++dc) {
    constexpr int z = 0;  // keep dc loop shape
    const int tlo = (dc == 0) ? KP0 : 0;
    const int thi = (dc == NCH - 1) ? (KP0 + 31 - 9 * (NCH - 1)) : 8;
#pragma unroll
    for (int di = 0; di < 3; ++di) {
      if (di >= tlo / 3 && di <= thi / 3)
        win[dc][di] = *(const f32x4u*)(pb + p0 + (c0 + dc) * PLANE + di * PITCH);
    }
    (void)z;
  }
  float v[32];
#pragma unroll
  for (int t = 0; t < 32; ++t) {
    const int idx = KP0 + t;
    const int dc = idx / 9, tap = idx % 9;
    v[t] = win[dc][tap / 3][tap % 3];
  }
  float mx = 0.f;
#pragma unroll
  for (int t = 0; t < 32; ++t) mx = fmaxf(mx, __builtin_fabsf(v[t]));
  const float r63 = (mx == 0.f) ? 0.f : 63.f / mx;
  const float scale = mx * (1.f / 63.f);
#pragma unroll
  for (int s = 0; s < 4; ++s) {
    u16x8 o;
#pragma unroll
    for (int e = 0; e < 8; ++e) {
      const float q = rintf(v[s * 8 + e] * r63);   // |q| <= 63 by construction
      o[e] = __builtin_bit_cast(unsigned short, __float2bfloat16(q * scale));
    }
    *(u16x8*)(as_row + ((cbase + (unsigned)(s * 16)) ^ swz)) = o;
  }
}

__device__ __forceinline__ void mfma_phase(
    const __hip_bfloat16* As, const __hip_bfloat16* Ns,
    f32x4 (&acc)[4][2], int wn, int wm, int lq, int hv, unsigned swq) {
#pragma unroll
  for (int kk = 0; kk < 2; ++kk) {
    const unsigned kobyte = (unsigned)(kk * 64 + hv * 16);
    bf16x8 af[4], bfr[2];
#pragma unroll
    for (int ifr = 0; ifr < 4; ++ifr) {
      const unsigned rn = (unsigned)(wn * 64 + ifr * 16 + lq);
      af[ifr] = *(const bf16x8*)((const char*)Ns + (rn * 128u + (kobyte ^ swq)));
    }
#pragma unroll
    for (int jfr = 0; jfr < 2; ++jfr) {
      const unsigned rm = (unsigned)(wm * 32 + jfr * 16 + lq);
      bfr[jfr] = *(const bf16x8*)((const char*)As + (rm * 128u + (kobyte ^ swq)));
    }
#pragma unroll
    for (int ifr = 0; ifr < 4; ++ifr)
#pragma unroll
      for (int jfr = 0; jfr < 2; ++jfr)
        acc[ifr][jfr] = __builtin_amdgcn_mfma_f32_16x16x32_bf16(
            af[ifr], bfr[jfr], acc[ifr][jfr], 0, 0, 0);
  }
}

// ---------------- Fused: unfold+quant-A + B-stage + GEMM + bias ----------------
// BM=64, BN=128, BK=64, 4 waves. Waves 0-1 quantize A (1 granule/thread, vector
// loads from padded x); waves 2-3 stage wqT via global_load_lds (pre-swizzled
// source). All waves MFMA (wave-tile 32m x 64n). 784 blocks, XCD-swizzled so
// each XCD owns one image (3.8MB xpad slab fits its 4MB L2).
__global__ __launch_bounds__(256, 3) void fused_gemm_kernel(
    const float* __restrict__ xpad, const __hip_bfloat16* __restrict__ wqT,
    const float* __restrict__ bias, float* __restrict__ out) {
  __shared__ __hip_bfloat16 As[64 * 64];    // 8KB, XOR-swizzled rows
  __shared__ __hip_bfloat16 Ns[128 * 64];   // 16KB, swizzled via source
  const int tid = threadIdx.x;
  const int lane = tid & 63;
  const int w = tid >> 6;

  const int bid = blockIdx.x;                      // 0..783
  const int swzb = (bid & 7) * 98 + (bid >> 3);    // bijective (784 % 8 == 0)
  const int mt = swzb >> 1;
  const int nt = swzb & 1;
  const int m0 = mt * 64;
  const int n1 = nt * 128;

  // quant geometry (waves 0,1): row = lane
  const int gm = m0 + lane;
  const int b = gm / LD;                    // uniform per block (LD%64==0)
  const int l = gm - b * LD;
  const int i = l / 56;
  const int j = l - i * 56;
  const float* pb = xpad + (size_t)b * CD * PLANE;
  const int p0 = i * PITCH + j;
  char* as_row = (char*)As + lane * 128;
  const unsigned swz_w = (unsigned)((lane & 7) << 4);
  const unsigned cbase = (unsigned)(w * 64);     // gh = w (bytes)

  // B-stage geometry (waves 2,3): pre-swizzled source column
  const int colsw = ((lane & 7) ^ (lane >> 3)) * 8;
  const unsigned short* wsrc = (const unsigned short*)wqT + (size_t)n1 * KD;

  // MFMA geometry
  const int lq = lane & 15, hv = lane >> 4;
  const int wn = w & 1, wm = w >> 1;
  const unsigned swq = (unsigned)((lq & 7) << 4);

  f32x4 acc[4][2] = {};

#define KSTEP(R)                                                              \
  {                                                                           \
    const int k0 = (s * 9 + (R)) * 64;                                        \
    if (w == 0) {                                                             \
      quant_granule<(64 * (R)) % 9>(pb, p0, s * 64 + (64 * (R)) / 9,          \
                                    as_row, cbase, swz_w);                    \
    } else if (w == 1) {                                                      \
      quant_granule<(64 * (R) + 32) % 9>(                                     \
          pb, p0, s * 64 + (64 * (R) + 32) / 9, as_row, cbase, swz_w);        \
    } else {                                                                  \
      const int wv = w - 2;                                                   \
      _Pragma("unroll") for (int sg = 0; sg < 8; ++sg) {                      \
        const int seg = sg * 2 + wv;                                          \
        const int rowN = seg * 8 + (lane >> 3);                               \
        gload_lds16(wsrc + (size_t)rowN * KD + k0 + colsw,                    \
                    (char*)Ns + seg * 1024 + (lane & 7) * 16 +                \
                        (lane >> 3) * 128);                                   \
      }                                                                       \
    }                                                                         \
    __syncthreads();                                                          \
    mfma_phase(As, Ns, acc, wn, wm, lq, hv, swq);                             \
    __syncthreads();                                                          \
  }

  for (int s = 0; s < 4; ++s) {
    KSTEP(0) KSTEP(1) KSTEP(2) KSTEP(3) KSTEP(4)
    KSTEP(5) KSTEP(6) KSTEP(7) KSTEP(8)
  }
#undef KSTEP

  // Epilogue: D row = n (hv*4 + comp), col = m (lq)
#pragma unroll
  for (int ifr = 0; ifr < 4; ++ifr) {
    const int nb = n1 + wn * 64 + ifr * 16 + hv * 4;
    const float4 b4 = *(const float4*)&bias[nb];
#pragma unroll
    for (int jfr = 0; jfr < 2; ++jfr) {
      const int m = m0 + wm * 32 + jfr * 16 + lq;
      const int ll = m - b * LD;
      float* op = out + ((size_t)b * ND + nb) * LD + ll;
      op[0]      = acc[ifr][jfr].x + b4.x;
      op[LD]     = acc[ifr][jfr].y + b4.y;
      op[2 * LD] = acc[ifr][jfr].z + b4.z;
      op[3 * LD] = acc[ifr][jfr].w + b4.w;
    }
  }
}

extern "C" void kernel_launch(void* const* d_in, const int* in_sizes, int n_in,
                              void* d_out, int out_size, void* d_ws, size_t ws_size,
                              hipStream_t stream) {
  const float* x = (const float*)d_in[0];
  const float* wgt = (const float*)d_in[1];
  const float* bias = (const float*)d_in[2];
  float* out = (float*)d_out;

  float* xpad = (float*)d_ws;                         // 8*256*3712*4 = 30,408,704 B
  __hip_bfloat16* wqT = (__hip_bfloat16*)((char*)d_ws + 30408704);  // 1,179,648 B

  pad_kernel<<<8 * CD, 256, 0, stream>>>(x, xpad);
  quant_w_kernel<<<576, 256, 0, stream>>>(wgt, wqT);
  fused_gemm_kernel<<<MD / 64 * 2, 256, 0, stream>>>(xpad, wqT, bias, out);
}